// Round 1
// baseline (187.329 us; speedup 1.0000x reference)
//
#include <hip/hip_runtime.h>

// out[b][i][j] = G[min(i,j)][max(i,j)] where
//   G[i][j] = sum_{i<=p<=q<=j} W[p][q],  W[p][p]=D[p][p], W[p][q]=D[p][q]+D[q][p] (q>p)
// except out[b][i][i-1] = D[b][i][i-1].
//
// Pass 1: R[p][q] = sum_{t=p..q} W[p][t]   (row prefix scan from diagonal)
// Pass 2: G[i][j] = sum_{p=i..j} R[p][j]   (column suffix scan up from diagonal),
//         writes out upper tile + transposed lower tile.
// Pass 3: patch subdiagonal with D.
// R is stored in d_out (in-place safe; see analysis in commit message).

__global__ __launch_bounds__(256) void pass1_rowscan(const float* __restrict__ D,
                                                     float* __restrict__ R,
                                                     int n, int npairs) {
    const int b = blockIdx.x / npairs;
    const int pair = blockIdx.x % npairs;
    const int nrb = 2 * npairs;              // row blocks per batch (n/32)
    const size_t nn = (size_t)n * n;
    const float* Db = D + (size_t)b * nn;
    float* Rb = R + (size_t)b * nn;

    __shared__ float ldsT[64 * 33];
    const int t = threadIdx.x;
    const int lane = t & 63;
    const int wave = t >> 6;
    const int nqt = n >> 6;

    for (int half = 0; half < 2; ++half) {
        const int bp = half ? (nrb - 1 - pair) : pair;   // pair long+short row blocks
        const int p0 = bp * 32;
        float carry[8];
#pragma unroll
        for (int r = 0; r < 8; ++r) carry[r] = 0.0f;
        for (int bq = (p0 >> 6); bq < nqt; ++bq) {
            const int q0 = bq * 64;
            __syncthreads();
            // stage column panel D[q0+qq][p0+pp] -> ldsT[qq][pp]  (coalesced load)
            {
                const int pp = t & 31;
                const int qq0 = t >> 5;
#pragma unroll
                for (int it = 0; it < 8; ++it) {
                    const int qq = qq0 + it * 8;
                    ldsT[qq * 33 + pp] = Db[(size_t)(q0 + qq) * n + (p0 + pp)];
                }
            }
            __syncthreads();
            float v[8];
#pragma unroll
            for (int r = 0; r < 8; ++r) {
                const int row = wave * 8 + r;
                const int gp = p0 + row;
                const int gq = q0 + lane;
                const float a = Db[(size_t)gp * n + gq];     // D[p][q], coalesced
                const float d2 = ldsT[lane * 33 + row];      // D[q][p] via LDS transpose
                v[r] = (gq > gp) ? (a + d2) : ((gq == gp) ? a : 0.0f);
            }
            // 8 independent inclusive scans along lanes (q direction)
#pragma unroll
            for (int d = 1; d < 64; d <<= 1) {
#pragma unroll
                for (int r = 0; r < 8; ++r) {
                    const float s = __shfl_up(v[r], d, 64);
                    if (lane >= d) v[r] += s;
                }
            }
#pragma unroll
            for (int r = 0; r < 8; ++r) {
                const int row = wave * 8 + r;
                const int gp = p0 + row;
                const int gq = q0 + lane;
                Rb[(size_t)gp * n + gq] = carry[r] + v[r];
                carry[r] += __shfl(v[r], 63, 64);
            }
        }
    }
}

__global__ __launch_bounds__(256) void pass2_colscan(const float* __restrict__ Rg,
                                                     float* __restrict__ out,
                                                     int n, int npairs) {
    const int b = blockIdx.x / npairs;
    const int pair = blockIdx.x % npairs;
    const int ncb = 2 * npairs;              // col blocks per batch (n/32)
    const size_t nn = (size_t)n * n;
    const float* Rb = Rg + (size_t)b * nn;
    float* Ob = out + (size_t)b * nn;

    __shared__ float lds[64 * 33];
    const int t = threadIdx.x;
    const int lane = t & 63;
    const int wave = t >> 6;

    for (int half = 0; half < 2; ++half) {
        const int bj = half ? (ncb - 1 - pair) : pair;
        const int c0 = bj * 32;
        float carry[8];
#pragma unroll
        for (int r = 0; r < 8; ++r) carry[r] = 0.0f;
        const int bi_top = (c0 + 31) >> 6;
        for (int bi = bi_top; bi >= 0; --bi) {
            const int i0 = bi * 64;
            __syncthreads();
            // load R tile [i0..i0+64) x [c0..c0+32)  (coalesced)
            {
                const int jj = t & 31;
                const int ii0 = t >> 5;
#pragma unroll
                for (int it = 0; it < 8; ++it) {
                    const int ii = ii0 + it * 8;
                    lds[ii * 33 + jj] = Rb[(size_t)(i0 + ii) * n + (c0 + jj)];
                }
            }
            __syncthreads();
            // suffix scan along i (lane) per column; each (wave,r) owns one column
            float g[8];
#pragma unroll
            for (int r = 0; r < 8; ++r) {
                const int jj = wave * 8 + r;
                const int gj = c0 + jj;
                const int gi = i0 + lane;
                float v = lds[lane * 33 + jj];
                v = (gi <= gj) ? v : 0.0f;   // mask below-diagonal garbage
#pragma unroll
                for (int d = 1; d < 64; d <<= 1) {
                    const float s = __shfl_down(v, d, 64);
                    if (lane + d < 64) v += s;
                }
                v += carry[r];
                carry[r] = __shfl(v, 0, 64);  // G at top row of tile feeds tile above
                g[r] = v;
            }
            // each lds element is read+written by the same thread -> no sync needed here
#pragma unroll
            for (int r = 0; r < 8; ++r) {
                const int jj = wave * 8 + r;
                lds[lane * 33 + jj] = g[r];
            }
            __syncthreads();
            // upper-triangle write: out[gi][gj] = G[gi][gj]
            {
                const int jj = t & 31;
                const int ii0 = t >> 5;
#pragma unroll
                for (int it = 0; it < 8; ++it) {
                    const int ii = ii0 + it * 8;
                    const int gi = i0 + ii, gj = c0 + jj;
                    if (gi <= gj) Ob[(size_t)gi * n + gj] = lds[ii * 33 + jj];
                }
            }
            // lower-triangle transposed write: out[gj][gi] = G[gi][gj]  (gi < gj)
            {
                const int ii = t & 63;
                const int jj0 = t >> 6;
#pragma unroll
                for (int it = 0; it < 8; ++it) {
                    const int jj = jj0 + it * 4;
                    const int gi = i0 + ii, gj = c0 + jj;
                    if (gi < gj) Ob[(size_t)gj * n + gi] = lds[ii * 33 + jj];
                }
            }
        }
    }
}

__global__ void patch_subdiag(const float* __restrict__ D, float* __restrict__ out,
                              int n, int B) {
    const int idx = blockIdx.x * blockDim.x + threadIdx.x;
    const int total = B * (n - 1);
    if (idx >= total) return;
    const int b = idx / (n - 1);
    const int i = idx % (n - 1) + 1;
    const size_t off = (size_t)b * n * n + (size_t)i * n + (i - 1);
    out[off] = D[off];
}

extern "C" void kernel_launch(void* const* d_in, const int* in_sizes, int n_in,
                              void* d_out, int out_size, void* d_ws, size_t ws_size,
                              hipStream_t stream) {
    const float* D = (const float*)d_in[0];
    float* out = (float*)d_out;
    const int n = 2048;
    const int B = in_sizes[0] / (n * n);
    const int npairs = (n / 32) / 2;   // 32 -> B*npairs = 256 workgroups, one per CU

    pass1_rowscan<<<dim3(B * npairs), dim3(256), 0, stream>>>(D, out, n, npairs);
    pass2_colscan<<<dim3(B * npairs), dim3(256), 0, stream>>>(out, out, n, npairs);

    const int total = B * (n - 1);
    patch_subdiag<<<dim3((total + 255) / 256), dim3(256), 0, stream>>>(D, out, n, B);
}

// Round 2
// 140.329 us; speedup vs baseline: 1.3349x; 1.3349x over previous
//
#include <hip/hip_runtime.h>

// out[b][i][j] = G[min(i,j)][max(i,j)], G[i][j] = sum_{i<=p<=q<=j} W[p][q],
// W[p][p]=D[p][p], W[p][q]=D[p][q]+D[q][p] (q>p); out[b][i][i-1]=D[b][i][i-1].
//
// Hierarchical two-axis scan, all tiles parallel:
//  K1: per 64x64 upper tile: local row prefix (R_local -> d_out),
//      rowTileSum[b][bq][p], colSumLocal[b][bp][bq][64]
//  K2: per row p: exclusive scan of rowTileSum over bq -> rowOff[b][bq][p];
//      tileOffSum[b][bi][bq] = sum_{p in tile bi} rowOff[p][bq]
//  K3: per column j: suffix scan over row-tiles of (colSumLocal + tileOffSum)
//      -> colCar[b][bi][j]
//  K4: per tile: R' = R_local + rowOff; within-tile column suffix + colCar;
//      write upper tile (float4) + transposed lower tile (coalesced).
//  K5: patch subdiagonal with D.

#define NT 32
#define TS 64

__global__ __launch_bounds__(256) void k1_rowscan(const float* __restrict__ D,
                                                  float* __restrict__ Rl,
                                                  float* __restrict__ rowTS,
                                                  float* __restrict__ colSL,
                                                  int n) {
    const int bp = blockIdx.x / NT, bq = blockIdx.x % NT;
    if (bq < bp) return;
    const int b = blockIdx.y;
    const size_t nn = (size_t)n * n;
    const float* Db = D + (size_t)b * nn;
    float* Rb = Rl + (size_t)b * nn;
    const int p0 = bp * TS, q0 = bq * TS;
    __shared__ float ldsT[TS * 65];
    __shared__ float cs[4][64];
    const int t = threadIdx.x;
    // stage D[q0..][p0..] transposed into LDS (float4 coalesced loads)
    {
        const int c4 = (t & 15) * 4, r0 = t >> 4;
#pragma unroll
        for (int pass = 0; pass < 4; ++pass) {
            const int ii = r0 + pass * 16;
            float4 v = *(const float4*)&Db[(size_t)(q0 + ii) * n + p0 + c4];
            ldsT[(c4 + 0) * 65 + ii] = v.x;
            ldsT[(c4 + 1) * 65 + ii] = v.y;
            ldsT[(c4 + 2) * 65 + ii] = v.z;
            ldsT[(c4 + 3) * 65 + ii] = v.w;
        }
    }
    __syncthreads();
    const int l = t & 63, w = t >> 6;
    float vals[16];
#pragma unroll
    for (int c = 0; c < 16; ++c) {
        const int row = w * 16 + c;
        const int gp = p0 + row, gq = q0 + l;
        const float a = Db[(size_t)gp * n + gq];      // D[p][q], coalesced
        const float at = ldsT[row * 65 + l];          // D[q][p]
        vals[c] = (gq > gp) ? (a + at) : ((gq == gp) ? a : 0.0f);
    }
#pragma unroll
    for (int d = 1; d < 64; d <<= 1) {
#pragma unroll
        for (int c = 0; c < 16; ++c) {
            const float s = __shfl_up(vals[c], d, 64);
            if (l >= d) vals[c] += s;
        }
    }
    float psum = 0.0f;
#pragma unroll
    for (int c = 0; c < 16; ++c) {
        const int row = w * 16 + c;
        const int gp = p0 + row, gq = q0 + l;
        Rb[(size_t)gp * n + gq] = vals[c];
        if (l == 63) rowTS[((size_t)b * NT + bq) * n + gp] = vals[c];
        psum += vals[c];
    }
    cs[w][l] = psum;
    __syncthreads();
    if (t < 64) {
        const float s = cs[0][t] + cs[1][t] + cs[2][t] + cs[3][t];
        colSL[(((size_t)b * NT + bp) * NT + bq) * 64 + t] = s;
    }
}

__global__ __launch_bounds__(64) void k2_rowoff(const float* __restrict__ rowTS,
                                                float* __restrict__ rowOff,
                                                float* __restrict__ tileOS,
                                                int n) {
    const int bi = blockIdx.x % NT;
    const int b  = blockIdx.x / NT;
    const int r = threadIdx.x;
    const int p = bi * TS + r;
    __shared__ float ldsO[64 * 33];
    float acc = 0.0f;
    for (int bq = 0; bq < NT; ++bq) {
        const float s = (bq >= bi) ? rowTS[((size_t)b * NT + bq) * n + p] : 0.0f;
        rowOff[((size_t)b * NT + bq) * n + p] = acc;
        ldsO[r * 33 + bq] = acc;
        acc += s;
    }
    __syncthreads();
    if (r < NT) {
        float s = 0.0f;
        for (int rr = 0; rr < 64; ++rr) s += ldsO[rr * 33 + r];
        tileOS[((size_t)b * NT + bi) * NT + r] = s;
    }
}

__global__ __launch_bounds__(64) void k3_colcarry(const float* __restrict__ colSL,
                                                  const float* __restrict__ tileOS,
                                                  float* __restrict__ colCar,
                                                  int n) {
    const int bq = blockIdx.x % NT;
    const int b  = blockIdx.x / NT;
    const int l = threadIdx.x;
    const int j = bq * TS + l;
    float carry = 0.0f;
    for (int bi = bq; bi >= 0; --bi) {
        colCar[((size_t)b * NT + bi) * n + j] = carry;
        const float C = colSL[(((size_t)b * NT + bi) * NT + bq) * 64 + l]
                      + tileOS[((size_t)b * NT + bi) * NT + bq];
        carry += C;
    }
}

__global__ __launch_bounds__(256) void k4_colscan(const float* __restrict__ Rl,
                                                  float* __restrict__ out,
                                                  const float* __restrict__ rowOff,
                                                  const float* __restrict__ colCar,
                                                  int n) {
    const int bi = blockIdx.x / NT, bq = blockIdx.x % NT;
    if (bq < bi) return;
    const int b = blockIdx.y;
    const size_t nn = (size_t)n * n;
    const float* Rb = Rl + (size_t)b * nn;
    float* Ob = out + (size_t)b * nn;
    const int i0 = bi * TS, q0 = bq * TS;
    __shared__ float lds[TS * 65];
    __shared__ float rO[64], cC[64];
    const int t = threadIdx.x;
    {
        const int c4 = (t & 15) * 4, r0 = t >> 4;
#pragma unroll
        for (int pass = 0; pass < 4; ++pass) {
            const int ii = r0 + pass * 16;
            float4 v = *(const float4*)&Rb[(size_t)(i0 + ii) * n + q0 + c4];
            lds[(c4 + 0) * 65 + ii] = v.x;
            lds[(c4 + 1) * 65 + ii] = v.y;
            lds[(c4 + 2) * 65 + ii] = v.z;
            lds[(c4 + 3) * 65 + ii] = v.w;
        }
    }
    if (t < 64) rO[t] = rowOff[((size_t)b * NT + bq) * n + i0 + t];
    else if (t < 128) cC[t - 64] = colCar[((size_t)b * NT + bi) * n + q0 + (t - 64)];
    __syncthreads();
    const int l = t & 63, w = t >> 6;
    float vals[16];
#pragma unroll
    for (int c = 0; c < 16; ++c) {
        const int jj = w * 16 + c;
        vals[c] = lds[jj * 65 + l] + rO[l];   // R'[i0+l][q0+jj]
    }
#pragma unroll
    for (int d = 1; d < 64; d <<= 1) {
#pragma unroll
        for (int c = 0; c < 16; ++c) {
            const float s = __shfl_down(vals[c], d, 64);
            if (l + d < 64) vals[c] += s;
        }
    }
    const bool diag = (bi == bq);
#pragma unroll
    for (int c = 0; c < 16; ++c) {
        const int jj = w * 16 + c;
        const float g = vals[c] + cC[jj];
        const int gi = i0 + l, gj = q0 + jj;
        if (gj > gi) Ob[(size_t)gj * n + gi] = g;  // lower transpose, coalesced over l
        lds[jj * 65 + l] = g;  // same thread wrote/read these addrs only -> no sync needed
    }
    __syncthreads();
    if (!diag) {
        const int c4 = (t & 15) * 4, r0 = t >> 4;
#pragma unroll
        for (int pass = 0; pass < 4; ++pass) {
            const int ii = r0 + pass * 16;
            float4 v;
            v.x = lds[(c4 + 0) * 65 + ii];
            v.y = lds[(c4 + 1) * 65 + ii];
            v.z = lds[(c4 + 2) * 65 + ii];
            v.w = lds[(c4 + 3) * 65 + ii];
            *(float4*)&Ob[(size_t)(i0 + ii) * n + q0 + c4] = v;
        }
    } else {
#pragma unroll
        for (int pass = 0; pass < 16; ++pass) {
            const int idx = pass * 256 + t;
            const int ii = idx >> 6, jj = idx & 63;
            if (ii <= jj) Ob[(size_t)(i0 + ii) * n + q0 + jj] = lds[jj * 65 + ii];
        }
    }
}

__global__ void patch_subdiag(const float* __restrict__ D, float* __restrict__ out,
                              int n, int B) {
    const int idx = blockIdx.x * blockDim.x + threadIdx.x;
    const int total = B * (n - 1);
    if (idx >= total) return;
    const int b = idx / (n - 1);
    const int i = idx % (n - 1) + 1;
    const size_t off = (size_t)b * n * n + (size_t)i * n + (i - 1);
    out[off] = D[off];
}

extern "C" void kernel_launch(void* const* d_in, const int* in_sizes, int n_in,
                              void* d_out, int out_size, void* d_ws, size_t ws_size,
                              hipStream_t stream) {
    const float* D = (const float*)d_in[0];
    float* out = (float*)d_out;
    const int n = 2048;
    const int B = in_sizes[0] / (n * n);

    float* ws = (float*)d_ws;
    const size_t szRowTS = (size_t)B * NT * n;       // 0.5M floats
    const size_t szColSL = (size_t)B * NT * NT * 64; // 0.5M floats
    const size_t szTOS   = (size_t)B * NT * NT;      // 8K floats
    float* rowTS  = ws;
    float* rowOff = rowTS + szRowTS;
    float* colSL  = rowOff + szRowTS;
    float* tileOS = colSL + szColSL;
    float* colCar = tileOS + szTOS;                  // B*NT*n floats

    dim3 gT(NT * NT, B);
    k1_rowscan<<<gT, dim3(256), 0, stream>>>(D, out, rowTS, colSL, n);
    k2_rowoff<<<dim3(B * NT), dim3(64), 0, stream>>>(rowTS, rowOff, tileOS, n);
    k3_colcarry<<<dim3(B * NT), dim3(64), 0, stream>>>(colSL, tileOS, colCar, n);
    k4_colscan<<<gT, dim3(256), 0, stream>>>(out, out, rowOff, colCar, n);

    const int total = B * (n - 1);
    patch_subdiag<<<dim3((total + 255) / 256), dim3(256), 0, stream>>>(D, out, n, B);
}

// Round 3
// 122.831 us; speedup vs baseline: 1.5251x; 1.1425x over previous
//
#include <hip/hip_runtime.h>

// out[b][i][j] = G[min(i,j)][max(i,j)], G[i][j] = sum_{i<=p<=q<=j} W[p][q],
// W[p][p]=D[p][p], W[p][q]=D[p][q]+D[q][p] (q>p); out[b][i][i-1]=D[b][i][i-1].
//
// k1: RS[b][ch][p]=sum_{q in ch}D[p][q], CS[b][ch][p]=sum_{q in ch}D[q][p]  (pure reduction)
// kdiag: per diag tile: mrow[p]=sum_{q>=p}W[p][q], mcps[j]=sum_{t<=j}sum_{p<=t}W[p][t]
// k2: rowOff[b][bq][p] = exclusive scan over chunks of rowTS (RS+CS off-diag, mrow diag);
//     tos[b][bi][bq] = sum_{p in bi} rowOff[bq][p]
// k3: colCar[b][bi][q0+j] via suffix over row-tiles of (prefix_j(RS+CS) + tos), top term mcps
// k4: recompute W from D (L3-hot), register-axis row prefix + rowOff, register-axis
//     col suffix + colCar, write upper + transposed lower. k5: patch subdiagonal.

#define NT 32
#define PD 65

__global__ __launch_bounds__(256) void k1_sums(const float* __restrict__ D,
                                               float* __restrict__ RS,
                                               float* __restrict__ CS, int n) {
    const int bq = blockIdx.x, b = blockIdx.y;
    const int q0 = bq * 64;
    const size_t nn = (size_t)n * n;
    const float* Db = D + (size_t)b * nn;
    __shared__ float Rlds[64 * 33];
    const int t = threadIdx.x;
    float cs[8];
#pragma unroll
    for (int e = 0; e < 8; ++e) cs[e] = 0.f;
    const float* base = Db + (size_t)q0 * n + 8 * t;
#pragma unroll 4
    for (int r = 0; r < 64; ++r) {
        float4 a0 = *(const float4*)(base + (size_t)r * n);
        float4 a1 = *(const float4*)(base + (size_t)r * n + 4);
        cs[0] += a0.x; cs[1] += a0.y; cs[2] += a0.z; cs[3] += a0.w;
        cs[4] += a1.x; cs[5] += a1.y; cs[6] += a1.z; cs[7] += a1.w;
        float rp = a0.x + a0.y + a0.z + a0.w + a1.x + a1.y + a1.z + a1.w;
        rp += __shfl_xor(rp, 1, 64);
        rp += __shfl_xor(rp, 2, 64);
        rp += __shfl_xor(rp, 4, 64);
        if ((t & 7) == 0) Rlds[r * 33 + (t >> 3)] = rp;
    }
    __syncthreads();
    {
        size_t cbase = ((size_t)b * NT + bq) * n + 8 * t;
        float4 c0 = {cs[0], cs[1], cs[2], cs[3]};
        float4 c1 = {cs[4], cs[5], cs[6], cs[7]};
        *(float4*)&CS[cbase] = c0;
        *(float4*)&CS[cbase + 4] = c1;
    }
#pragma unroll
    for (int m = 0; m < 8; ++m) {
        const int idx = 256 * m + t;
        const int r = idx & 63, ch = idx >> 6;
        RS[((size_t)b * NT + ch) * n + q0 + r] = Rlds[r * 33 + ch];
    }
}

__global__ __launch_bounds__(256) void k_diag(const float* __restrict__ D,
                                              float* __restrict__ mrow,
                                              float* __restrict__ mcps, int n) {
    const int bt = blockIdx.x, b = blockIdx.y;
    const int o = bt * 64;
    const size_t nn = (size_t)n * n;
    const float* Db = D + (size_t)b * nn;
    __shared__ float Tl[64 * PD];
    __shared__ float s1[4 * 64], s2[4 * 64];
    const int t = threadIdx.x;
    {
        const int c4 = (t & 15) * 4, r0 = t >> 4;
#pragma unroll
        for (int m = 0; m < 4; ++m) {
            const int row = r0 + 16 * m;
            float4 v = *(const float4*)&Db[(size_t)(o + row) * n + o + c4];
            Tl[row * PD + c4 + 0] = v.x;
            Tl[row * PD + c4 + 1] = v.y;
            Tl[row * PD + c4 + 2] = v.z;
            Tl[row * PD + c4 + 3] = v.w;
        }
    }
    __syncthreads();
    const int p = t & 63, s = t >> 6;
    float mr = 0.f, mc = 0.f;
#pragma unroll
    for (int k = 0; k < 16; ++k) {
        const int q = 16 * s + k;
        const float va = Tl[p * PD + q];
        const float vb = Tl[q * PD + p];
        if (q > p) mr += va + vb;
        else if (q < p) mc += va + vb;
        else { mr += va; mc += va; }
    }
    s1[s * 64 + p] = mr;
    s2[s * 64 + p] = mc;
    __syncthreads();
    if (t < 64) {
        float rsum = s1[t] + s1[64 + t] + s1[128 + t] + s1[192 + t];
        float csum = s2[t] + s2[64 + t] + s2[128 + t] + s2[192 + t];
        mrow[((size_t)b * NT + bt) * 64 + t] = rsum;
#pragma unroll
        for (int d = 1; d < 64; d <<= 1) {
            float o2 = __shfl_up(csum, d, 64);
            if (t >= d) csum += o2;
        }
        mcps[((size_t)b * NT + bt) * 64 + t] = csum;
    }
}

__global__ __launch_bounds__(64) void k2_rowoff(const float* __restrict__ RS,
                                                const float* __restrict__ CS,
                                                const float* __restrict__ mrow,
                                                float* __restrict__ rowOff,
                                                float* __restrict__ tos, int n) {
    const int bi = blockIdx.x, b = blockIdx.y;
    const int t = threadIdx.x;
    const int p = bi * 64 + t;
    __shared__ float ldsO[64 * 33];
    float acc = 0.f;
    for (int bq = 0; bq < NT; ++bq) {
        rowOff[((size_t)b * NT + bq) * n + p] = acc;
        ldsO[t * 33 + bq] = acc;
        float sv;
        if (bq < bi) sv = 0.f;
        else if (bq == bi) sv = mrow[((size_t)b * NT + bi) * 64 + t];
        else sv = RS[((size_t)b * NT + bq) * n + p] + CS[((size_t)b * NT + bq) * n + p];
        acc += sv;
    }
    __syncthreads();
    if (t < NT) {
        float s = 0.f;
        for (int r = 0; r < 64; ++r) s += ldsO[r * 33 + t];
        tos[((size_t)b * NT + bi) * NT + t] = s;
    }
}

__global__ __launch_bounds__(64) void k3_colcar(const float* __restrict__ RS,
                                                const float* __restrict__ CS,
                                                const float* __restrict__ mcps,
                                                const float* __restrict__ tos,
                                                float* __restrict__ colCar, int n) {
    const int bq = blockIdx.x, b = blockIdx.y;
    const int j = threadIdx.x;
    const int q0 = bq * 64;
    colCar[((size_t)b * NT + bq) * n + q0 + j] = 0.f;
    if (bq == 0) return;
    float carry = mcps[((size_t)b * NT + bq) * 64 + j];
    colCar[((size_t)b * NT + (bq - 1)) * n + q0 + j] = carry;
    for (int bi = bq - 1; bi >= 1; --bi) {
        float cw = RS[((size_t)b * NT + bi) * n + q0 + j]
                 + CS[((size_t)b * NT + bi) * n + q0 + j];
#pragma unroll
        for (int d = 1; d < 64; d <<= 1) {
            float o2 = __shfl_up(cw, d, 64);
            if (j >= d) cw += o2;
        }
        carry += cw + tos[((size_t)b * NT + bi) * NT + bq];
        colCar[((size_t)b * NT + (bi - 1)) * n + q0 + j] = carry;
    }
}

__global__ __launch_bounds__(256) void k4_tile(const float* __restrict__ D,
                                               float* __restrict__ out,
                                               const float* __restrict__ rowOff,
                                               const float* __restrict__ colCar, int n) {
    const int bi = blockIdx.x / NT, bq = blockIdx.x % NT;
    if (bq < bi) return;
    const int b = blockIdx.y;
    const int i0 = bi * 64, q0 = bq * 64;
    const bool dg = (bi == bq);
    const size_t nn = (size_t)n * n;
    const float* Db = D + (size_t)b * nn;
    float* Ob = out + (size_t)b * nn;
    __shared__ float Al[64 * PD];
    __shared__ float Bl[64 * PD];
    __shared__ float st1[4 * 64], st2[4 * 64];
    __shared__ float rOl[64], cCl[64];
    const int t = threadIdx.x;
    {
        const int c4 = (t & 15) * 4, r0 = t >> 4;
#pragma unroll
        for (int m = 0; m < 4; ++m) {
            const int row = r0 + 16 * m;
            float4 va = *(const float4*)&Db[(size_t)(i0 + row) * n + q0 + c4];
            Al[row * PD + c4 + 0] = va.x;
            Al[row * PD + c4 + 1] = va.y;
            Al[row * PD + c4 + 2] = va.z;
            Al[row * PD + c4 + 3] = va.w;
            float4 vb = *(const float4*)&Db[(size_t)(q0 + row) * n + i0 + c4];
            Bl[row * PD + c4 + 0] = vb.x;
            Bl[row * PD + c4 + 1] = vb.y;
            Bl[row * PD + c4 + 2] = vb.z;
            Bl[row * PD + c4 + 3] = vb.w;
        }
    }
    if (t < 64) rOl[t] = rowOff[((size_t)b * NT + bq) * n + i0 + t];
    else if (t < 128) cCl[t - 64] = colCar[((size_t)b * NT + bi) * n + q0 + (t - 64)];
    __syncthreads();
    const int lp = t & 63, s = t >> 6;
    // row phase: row lp, cols 16s..16s+16
    float v[16];
    {
        float run = 0.f;
#pragma unroll
        for (int k = 0; k < 16; ++k) {
            const int q = 16 * s + k;
            const float a = Al[lp * PD + q];
            const float bb = Bl[q * PD + lp];
            float w = a + bb;
            if (dg) w = (q > lp) ? w : ((q == lp) ? a : 0.f);
            run += w;
            v[k] = run;
        }
        st1[s * 64 + lp] = run;
    }
    __syncthreads();
    {
        float off = rOl[lp];
        if (s > 0) off += st1[0 * 64 + lp];
        if (s > 1) off += st1[1 * 64 + lp];
        if (s > 2) off += st1[2 * 64 + lp];
#pragma unroll
        for (int k = 0; k < 16; ++k) Al[lp * PD + 16 * s + k] = v[k] + off;
    }
    __syncthreads();
    // col phase: column lp, rows 16s..16s+16
    float g[16];
#pragma unroll
    for (int k = 0; k < 16; ++k) g[k] = Al[(16 * s + k) * PD + lp];
#pragma unroll
    for (int k = 14; k >= 0; --k) g[k] += g[k + 1];
    st2[s * 64 + lp] = g[0];
    __syncthreads();
    {
        float off = cCl[lp];
        if (s < 1) off += st2[1 * 64 + lp];
        if (s < 2) off += st2[2 * 64 + lp];
        if (s < 3) off += st2[3 * 64 + lp];
#pragma unroll
        for (int k = 0; k < 16; ++k) Bl[lp * PD + 16 * s + k] = g[k] + off;  // Bl[q][p]=G[p][q]
    }
    __syncthreads();
    if (!dg) {
        const int c4 = (t & 15) * 4, r0 = t >> 4;
#pragma unroll
        for (int m = 0; m < 4; ++m) {
            const int row = r0 + 16 * m;
            float4 u;
            u.x = Bl[(c4 + 0) * PD + row];
            u.y = Bl[(c4 + 1) * PD + row];
            u.z = Bl[(c4 + 2) * PD + row];
            u.w = Bl[(c4 + 3) * PD + row];
            *(float4*)&Ob[(size_t)(i0 + row) * n + q0 + c4] = u;
            float4 l4;
            l4.x = Bl[row * PD + c4 + 0];
            l4.y = Bl[row * PD + c4 + 1];
            l4.z = Bl[row * PD + c4 + 2];
            l4.w = Bl[row * PD + c4 + 3];
            *(float4*)&Ob[(size_t)(q0 + row) * n + i0 + c4] = l4;
        }
    } else {
#pragma unroll
        for (int m = 0; m < 16; ++m) {
            const int idx = 256 * m + t;
            const int row = idx >> 6, col = idx & 63;
            const float val = (col >= row) ? Bl[col * PD + row] : Bl[row * PD + col];
            Ob[(size_t)(i0 + row) * n + q0 + col] = val;
        }
    }
}

__global__ void patch_subdiag(const float* __restrict__ D, float* __restrict__ out,
                              int n, int B) {
    const int idx = blockIdx.x * blockDim.x + threadIdx.x;
    const int total = B * (n - 1);
    if (idx >= total) return;
    const int b = idx / (n - 1);
    const int i = idx % (n - 1) + 1;
    const size_t off = (size_t)b * n * n + (size_t)i * n + (i - 1);
    out[off] = D[off];
}

extern "C" void kernel_launch(void* const* d_in, const int* in_sizes, int n_in,
                              void* d_out, int out_size, void* d_ws, size_t ws_size,
                              hipStream_t stream) {
    const float* D = (const float*)d_in[0];
    float* out = (float*)d_out;
    const int n = 2048;
    const int B = in_sizes[0] / (n * n);

    float* ws = (float*)d_ws;
    const size_t szRC = (size_t)B * NT * n;
    float* RS     = ws;
    float* CS     = RS + szRC;
    float* mrow   = CS + szRC;
    float* mcps   = mrow + (size_t)B * NT * 64;
    float* rowOff = mcps + (size_t)B * NT * 64;
    float* tos    = rowOff + szRC;
    float* colCar = tos + (size_t)B * NT * NT;

    k1_sums<<<dim3(NT, B), dim3(256), 0, stream>>>(D, RS, CS, n);
    k_diag<<<dim3(NT, B), dim3(256), 0, stream>>>(D, mrow, mcps, n);
    k2_rowoff<<<dim3(NT, B), dim3(64), 0, stream>>>(RS, CS, mrow, rowOff, tos, n);
    k3_colcar<<<dim3(NT, B), dim3(64), 0, stream>>>(RS, CS, mcps, tos, colCar, n);
    k4_tile<<<dim3(NT * NT, B), dim3(256), 0, stream>>>(D, out, rowOff, colCar, n);

    const int total = B * (n - 1);
    patch_subdiag<<<dim3((total + 255) / 256), dim3(256), 0, stream>>>(D, out, n, B);
}

// Round 4
// 111.350 us; speedup vs baseline: 1.6823x; 1.1031x over previous
//
#include <hip/hip_runtime.h>

// out[b][i][j] = G[min(i,j)][max(i,j)], G[i][j] = sum_{i<=p<=q<=j} W[p][q],
// W[p][p]=D[p][p], W[p][q]=D[p][q]+D[q][p] (q>p); out[b][i][i-1]=D[b][i][i-1].
//
// k1 (tile-parallel, 1024 tiles): RS[v][p]=sum_{q in chunk v}D[p][q] (tile (u,v) owns
//     p in chunk u), CS[u][j]=sum_{q in chunk u}D[q][j]; diag tiles emit mrow/mcps.
// k2: rowOff[bq][p] exclusive chunk-scan; tos[bi][bq]=sum_{p in bi} rowOff[bq][p].
// k3: colCar[bi][q0+j] suffix over row-chunks of (prefix_j(RS+CS)+tos), top=mcps.
// k4: W rebuilt from D (L3-hot) in one LDS buffer, register row-prefix + col-suffix,
//     writes upper + mirrored lower; subdiagonal patched inline.

#define NT 32
#define PD 65

__global__ __launch_bounds__(256) void k1_sums(const float* __restrict__ D,
                                               float* __restrict__ RS,
                                               float* __restrict__ CS,
                                               float* __restrict__ mrow,
                                               float* __restrict__ mcps, int n) {
    const int u = blockIdx.x / NT, v = blockIdx.x % NT;
    const int b = blockIdx.y;
    const size_t nn = (size_t)n * n;
    const float* Db = D + (size_t)b * nn;
    __shared__ float Tl[64 * PD];
    __shared__ float s1[4 * 64], s2[4 * 64];
    const int t = threadIdx.x;
    const int c4 = (t & 15) * 4, r0 = t >> 4;
    const int row0 = u * 64, col0 = v * 64;
#pragma unroll
    for (int m = 0; m < 4; ++m) {
        const int r = r0 + 16 * m;
        float4 a = *(const float4*)&Db[(size_t)(row0 + r) * n + col0 + c4];
        Tl[r * PD + c4 + 0] = a.x;
        Tl[r * PD + c4 + 1] = a.y;
        Tl[r * PD + c4 + 2] = a.z;
        Tl[r * PD + c4 + 3] = a.w;
    }
    __syncthreads();
    const int p = t & 63, s = t >> 6;
    if (u != v) {
        float pr = 0.f, pc = 0.f;
#pragma unroll
        for (int k = 0; k < 16; ++k) {
            const int q = 16 * s + k;
            pr += Tl[p * PD + q];
            pc += Tl[q * PD + p];
        }
        s1[s * 64 + p] = pr;
        s2[s * 64 + p] = pc;
        __syncthreads();
        if (t < 64) {
            RS[((size_t)b * NT + v) * n + row0 + t] =
                s1[t] + s1[64 + t] + s1[128 + t] + s1[192 + t];
        } else if (t < 128) {
            const int j = t - 64;
            CS[((size_t)b * NT + u) * n + col0 + j] =
                s2[j] + s2[64 + j] + s2[128 + j] + s2[192 + j];
        }
    } else {
        float mr = 0.f, mc = 0.f;
#pragma unroll
        for (int k = 0; k < 16; ++k) {
            const int q = 16 * s + k;
            const float va = Tl[p * PD + q];
            const float vb = Tl[q * PD + p];
            if (q > p) mr += va + vb;
            else if (q < p) mc += va + vb;
            else { mr += va; mc += va; }
        }
        s1[s * 64 + p] = mr;
        s2[s * 64 + p] = mc;
        __syncthreads();
        if (t < 64) {
            float rsum = s1[t] + s1[64 + t] + s1[128 + t] + s1[192 + t];
            float csum = s2[t] + s2[64 + t] + s2[128 + t] + s2[192 + t];
            mrow[((size_t)b * NT + u) * 64 + t] = rsum;
#pragma unroll
            for (int d = 1; d < 64; d <<= 1) {
                float o2 = __shfl_up(csum, d, 64);
                if (t >= d) csum += o2;
            }
            mcps[((size_t)b * NT + u) * 64 + t] = csum;
        }
    }
}

__global__ __launch_bounds__(64) void k2_rowoff(const float* __restrict__ RS,
                                                const float* __restrict__ CS,
                                                const float* __restrict__ mrow,
                                                float* __restrict__ rowOff,
                                                float* __restrict__ tos, int n) {
    const int bi = blockIdx.x, b = blockIdx.y;
    const int t = threadIdx.x;
    const int p = bi * 64 + t;
    float sv[NT];
#pragma unroll
    for (int bq = 0; bq < NT; ++bq) {
        if (bq > bi)
            sv[bq] = RS[((size_t)b * NT + bq) * n + p] + CS[((size_t)b * NT + bq) * n + p];
        else if (bq == bi)
            sv[bq] = mrow[((size_t)b * NT + bi) * 64 + t];
        else
            sv[bq] = 0.f;
    }
    float acc = 0.f, tosv = 0.f;
#pragma unroll
    for (int bq = 0; bq < NT; ++bq) {
        rowOff[((size_t)b * NT + bq) * n + p] = acc;
        float r = acc;
        r += __shfl_xor(r, 1, 64);
        r += __shfl_xor(r, 2, 64);
        r += __shfl_xor(r, 4, 64);
        r += __shfl_xor(r, 8, 64);
        r += __shfl_xor(r, 16, 64);
        r += __shfl_xor(r, 32, 64);
        if (t == bq) tosv = r;
        acc += sv[bq];
    }
    if (t < NT) tos[((size_t)b * NT + bi) * NT + t] = tosv;
}

__global__ __launch_bounds__(64) void k3_colcar(const float* __restrict__ RS,
                                                const float* __restrict__ CS,
                                                const float* __restrict__ mcps,
                                                const float* __restrict__ tos,
                                                float* __restrict__ colCar, int n) {
    const int bq = blockIdx.x, b = blockIdx.y;
    const int j = threadIdx.x;
    const int q0 = bq * 64;
    colCar[((size_t)b * NT + bq) * n + q0 + j] = 0.f;
    if (bq == 0) return;
    float rv[NT];
#pragma unroll
    for (int bi = 1; bi < NT; ++bi) {
        if (bi < bq) {
            float cw = RS[((size_t)b * NT + bi) * n + q0 + j]
                     + CS[((size_t)b * NT + bi) * n + q0 + j];
#pragma unroll
            for (int d = 1; d < 64; d <<= 1) {
                float o2 = __shfl_up(cw, d, 64);
                if (j >= d) cw += o2;
            }
            rv[bi] = cw;
        } else {
            rv[bi] = 0.f;
        }
    }
    float carry = mcps[((size_t)b * NT + bq) * 64 + j];
    colCar[((size_t)b * NT + (bq - 1)) * n + q0 + j] = carry;
#pragma unroll
    for (int bi = NT - 1; bi >= 1; --bi) {
        if (bi <= bq - 1) {
            carry += rv[bi] + tos[((size_t)b * NT + bi) * NT + bq];
            colCar[((size_t)b * NT + (bi - 1)) * n + q0 + j] = carry;
        }
    }
}

__global__ __launch_bounds__(256) void k4_tile(const float* __restrict__ D,
                                               float* __restrict__ out,
                                               const float* __restrict__ rowOff,
                                               const float* __restrict__ colCar, int n) {
    const int bi = blockIdx.x / NT, bq = blockIdx.x % NT;
    if (bq < bi) return;
    const int b = blockIdx.y;
    const int i0 = bi * 64, q0 = bq * 64;
    const bool dg = (bi == bq);
    const size_t nn = (size_t)n * n;
    const float* Db = D + (size_t)b * nn;
    float* Ob = out + (size_t)b * nn;
    __shared__ float Al[64 * PD];
    __shared__ float st1[4 * 64], st2[4 * 64];
    __shared__ float rOl[64], cCl[64];
    const int t = threadIdx.x;
    const int c4 = (t & 15) * 4, r0 = t >> 4;
    // issue all global loads early (T14): A tile + mirror tile
    float4 va[4], vb[4];
#pragma unroll
    for (int m = 0; m < 4; ++m) {
        const int r = r0 + 16 * m;
        va[m] = *(const float4*)&Db[(size_t)(i0 + r) * n + q0 + c4];
    }
    if (!dg) {
#pragma unroll
        for (int m = 0; m < 4; ++m) {
            const int r = r0 + 16 * m;
            vb[m] = *(const float4*)&Db[(size_t)(q0 + r) * n + i0 + c4];
        }
    }
#pragma unroll
    for (int m = 0; m < 4; ++m) {
        const int r = r0 + 16 * m;
        Al[r * PD + c4 + 0] = va[m].x;
        Al[r * PD + c4 + 1] = va[m].y;
        Al[r * PD + c4 + 2] = va[m].z;
        Al[r * PD + c4 + 3] = va[m].w;
    }
    if (t < 64) rOl[t] = rowOff[((size_t)b * NT + bq) * n + i0 + t];
    else if (t < 128) cCl[t - 64] = colCar[((size_t)b * NT + bi) * n + q0 + (t - 64)];
    __syncthreads();
    if (!dg) {
        // W[r][c] = A[r][c] + D[q0+c][i0+r]: add mirror transposed in place
#pragma unroll
        for (int m = 0; m < 4; ++m) {
            const int r = r0 + 16 * m;
            Al[(c4 + 0) * PD + r] += vb[m].x;
            Al[(c4 + 1) * PD + r] += vb[m].y;
            Al[(c4 + 2) * PD + r] += vb[m].z;
            Al[(c4 + 3) * PD + r] += vb[m].w;
        }
        __syncthreads();
    }
    const int lp = t & 63, s = t >> 6;
    // row phase: row lp, cols 16s..16s+15
    float v[16];
    {
        float run = 0.f;
#pragma unroll
        for (int k = 0; k < 16; ++k) {
            const int q = 16 * s + k;
            float w;
            if (dg) {
                const float a = Al[lp * PD + q];
                const float at = Al[q * PD + lp];
                w = (q > lp) ? (a + at) : ((q == lp) ? a : 0.f);
            } else {
                w = Al[lp * PD + q];
            }
            run += w;
            v[k] = run;
        }
        st1[s * 64 + lp] = run;
    }
    __syncthreads();
    {
        float off = rOl[lp];
        if (s > 0) off += st1[0 * 64 + lp];
        if (s > 1) off += st1[1 * 64 + lp];
        if (s > 2) off += st1[2 * 64 + lp];
#pragma unroll
        for (int k = 0; k < 16; ++k) Al[lp * PD + 16 * s + k] = v[k] + off;
    }
    __syncthreads();
    // col phase: column lp, rows 16s..16s+15, suffix scan
    float g[16];
#pragma unroll
    for (int k = 0; k < 16; ++k) g[k] = Al[(16 * s + k) * PD + lp];
#pragma unroll
    for (int k = 14; k >= 0; --k) g[k] += g[k + 1];
    st2[s * 64 + lp] = g[0];
    __syncthreads();
    {
        float off = cCl[lp];
        if (s < 1) off += st2[1 * 64 + lp];
        if (s < 2) off += st2[2 * 64 + lp];
        if (s < 3) off += st2[3 * 64 + lp];
        // write G transposed: Al[c][r] = G[r][c]  (c=lp, r=16s+k)
#pragma unroll
        for (int k = 0; k < 16; ++k) Al[lp * PD + 16 * s + k] = g[k] + off;
    }
    __syncthreads();
    if (!dg) {
#pragma unroll
        for (int m = 0; m < 4; ++m) {
            const int r = r0 + 16 * m;
            float4 uu;
            uu.x = Al[(c4 + 0) * PD + r];
            uu.y = Al[(c4 + 1) * PD + r];
            uu.z = Al[(c4 + 2) * PD + r];
            uu.w = Al[(c4 + 3) * PD + r];
            *(float4*)&Ob[(size_t)(i0 + r) * n + q0 + c4] = uu;
            float4 l4;
            l4.x = Al[r * PD + c4 + 0];
            l4.y = Al[r * PD + c4 + 1];
            l4.z = Al[r * PD + c4 + 2];
            l4.w = Al[r * PD + c4 + 3];
            // boundary subdiagonal element out[q0][q0-1] lives in tile (bi, bi+1)
            if (bq == bi + 1 && r == 0 && c4 == 60) l4.w = Db[(size_t)q0 * n + (q0 - 1)];
            *(float4*)&Ob[(size_t)(q0 + r) * n + i0 + c4] = l4;
        }
    } else {
#pragma unroll
        for (int m = 0; m < 16; ++m) {
            const int idx = 256 * m + t;
            const int rr = idx >> 6, cc = idx & 63;
            float val = (cc >= rr) ? Al[cc * PD + rr] : Al[rr * PD + cc];
            if (cc == rr - 1) val = Db[(size_t)(i0 + rr) * n + (i0 + cc)];
            Ob[(size_t)(i0 + rr) * n + q0 + cc] = val;
        }
    }
}

extern "C" void kernel_launch(void* const* d_in, const int* in_sizes, int n_in,
                              void* d_out, int out_size, void* d_ws, size_t ws_size,
                              hipStream_t stream) {
    const float* D = (const float*)d_in[0];
    float* out = (float*)d_out;
    const int n = 2048;
    const int B = in_sizes[0] / (n * n);

    float* ws = (float*)d_ws;
    const size_t szRC = (size_t)B * NT * n;
    float* RS     = ws;
    float* CS     = RS + szRC;
    float* mrow   = CS + szRC;
    float* mcps   = mrow + (size_t)B * NT * 64;
    float* rowOff = mcps + (size_t)B * NT * 64;
    float* tos    = rowOff + szRC;
    float* colCar = tos + (size_t)B * NT * NT;

    k1_sums<<<dim3(NT * NT, B), dim3(256), 0, stream>>>(D, RS, CS, mrow, mcps, n);
    k2_rowoff<<<dim3(NT, B), dim3(64), 0, stream>>>(RS, CS, mrow, rowOff, tos, n);
    k3_colcar<<<dim3(NT, B), dim3(64), 0, stream>>>(RS, CS, mcps, tos, colCar, n);
    k4_tile<<<dim3(NT * NT, B), dim3(256), 0, stream>>>(D, out, rowOff, colCar, n);
}

// Round 5
// 88.037 us; speedup vs baseline: 2.1278x; 1.2648x over previous
//
#include <hip/hip_runtime.h>

// out[b][i][j] = G[min(i,j)][max(i,j)], G[i][j] = sum_{i<=p<=q<=j} W[p][q],
// W[p][p]=D[p][p], W[p][q]=D[p][q]+D[q][p] (q>p), W=0 below diag;
// out[b][i][i-1]=D[b][i][i-1].
//
// k1 (528 upper tiles/batch): W tile -> d_out upper positions (in-place scratch);
//     rowW[v][p] (row-chunk sums), colW[u][j] (col-chunk sums), TS[u][v] (tile total).
// k23: half-A: rowOff[bq][p] = exclusive chunk-scan of rowW;
//      half-B: colCar[bi][j] = suffix over row-chunks of (prefix_j(colW) + tos),
//              tos[bi][bq] = sum_{v=bi..bq-1} TS[bi][v] (TS[bi][bi] is masked-diag total).
// k4 (528 tiles): read W tile from d_out (L3-hot), branch-free row prefix + col suffix,
//     write upper + mirrored lower in place; subdiagonal patched inline.

#define NT 32
#define PD 65

__device__ __forceinline__ void tri_decode(int m, int& u, int& v) {
    int u_ = 0, rem = m;
    while (rem >= NT - u_) { rem -= NT - u_; ++u_; }
    u = u_;
    v = u_ + rem;
}

__global__ __launch_bounds__(256) void k1_w(const float* __restrict__ D,
                                            float* __restrict__ Mout,
                                            float* __restrict__ rowW,
                                            float* __restrict__ colW,
                                            float* __restrict__ TS, int n) {
    int u, v;
    tri_decode(blockIdx.x, u, v);
    const int b = blockIdx.y;
    const size_t nn = (size_t)n * n;
    const float* Db = D + (size_t)b * nn;
    float* Mb = Mout + (size_t)b * nn;
    __shared__ float Tl[64 * PD];
    __shared__ float s1[64];
    __shared__ float s2[4 * 64];
    const int t = threadIdx.x;
    const int c4 = (t & 15) * 4, r0 = t >> 4;
    const int i0 = u * 64, q0 = v * 64;
    const bool dg = (u == v);
    float4 va[4], vb[4];
#pragma unroll
    for (int m = 0; m < 4; ++m)
        va[m] = *(const float4*)&Db[(size_t)(i0 + r0 + 16 * m) * n + q0 + c4];
    if (!dg) {
#pragma unroll
        for (int m = 0; m < 4; ++m)
            vb[m] = *(const float4*)&Db[(size_t)(q0 + r0 + 16 * m) * n + i0 + c4];
    } else {
#pragma unroll
        for (int m = 0; m < 4; ++m) vb[m] = va[m];
    }
#pragma unroll
    for (int m = 0; m < 4; ++m) {
        const int rr = r0 + 16 * m;
        Tl[rr * PD + c4 + 0] = vb[m].x;
        Tl[rr * PD + c4 + 1] = vb[m].y;
        Tl[rr * PD + c4 + 2] = vb[m].z;
        Tl[rr * PD + c4 + 3] = vb[m].w;
    }
    __syncthreads();
    float cs0 = 0.f, cs1 = 0.f, cs2 = 0.f, cs3 = 0.f;
#pragma unroll
    for (int m = 0; m < 4; ++m) {
        const int r = r0 + 16 * m;
        float w0 = va[m].x + Tl[(c4 + 0) * PD + r];
        float w1 = va[m].y + Tl[(c4 + 1) * PD + r];
        float w2 = va[m].z + Tl[(c4 + 2) * PD + r];
        float w3 = va[m].w + Tl[(c4 + 3) * PD + r];
        if (dg) {
            w0 = (c4 + 0 > r) ? w0 : ((c4 + 0 == r) ? va[m].x : 0.f);
            w1 = (c4 + 1 > r) ? w1 : ((c4 + 1 == r) ? va[m].y : 0.f);
            w2 = (c4 + 2 > r) ? w2 : ((c4 + 2 == r) ? va[m].z : 0.f);
            w3 = (c4 + 3 > r) ? w3 : ((c4 + 3 == r) ? va[m].w : 0.f);
        }
        float4 wv = {w0, w1, w2, w3};
        *(float4*)&Mb[(size_t)(i0 + r) * n + q0 + c4] = wv;
        float rsum = w0 + w1 + w2 + w3;
        rsum += __shfl_xor(rsum, 1, 64);
        rsum += __shfl_xor(rsum, 2, 64);
        rsum += __shfl_xor(rsum, 4, 64);
        rsum += __shfl_xor(rsum, 8, 64);
        if ((t & 15) == 0) s1[r] = rsum;
        cs0 += w0; cs1 += w1; cs2 += w2; cs3 += w3;
    }
    cs0 += __shfl_xor(cs0, 16, 64); cs0 += __shfl_xor(cs0, 32, 64);
    cs1 += __shfl_xor(cs1, 16, 64); cs1 += __shfl_xor(cs1, 32, 64);
    cs2 += __shfl_xor(cs2, 16, 64); cs2 += __shfl_xor(cs2, 32, 64);
    cs3 += __shfl_xor(cs3, 16, 64); cs3 += __shfl_xor(cs3, 32, 64);
    const int wv_ = t >> 6, l = t & 63;
    if (l < 16) {
        s2[wv_ * 64 + 4 * l + 0] = cs0;
        s2[wv_ * 64 + 4 * l + 1] = cs1;
        s2[wv_ * 64 + 4 * l + 2] = cs2;
        s2[wv_ * 64 + 4 * l + 3] = cs3;
    }
    __syncthreads();
    if (t < 64) {
        rowW[((size_t)b * NT + v) * n + i0 + t] = s1[t];
        float cw = s2[t] + s2[64 + t] + s2[128 + t] + s2[192 + t];
        colW[((size_t)b * NT + u) * n + q0 + t] = cw;
        float ts = cw;
        ts += __shfl_xor(ts, 1, 64);
        ts += __shfl_xor(ts, 2, 64);
        ts += __shfl_xor(ts, 4, 64);
        ts += __shfl_xor(ts, 8, 64);
        ts += __shfl_xor(ts, 16, 64);
        ts += __shfl_xor(ts, 32, 64);
        if (t == 0) TS[((size_t)b * NT + u) * NT + v] = ts;
    }
}

__global__ __launch_bounds__(128) void k23(const float* __restrict__ rowW,
                                           const float* __restrict__ colW,
                                           const float* __restrict__ TS,
                                           float* __restrict__ rowOff,
                                           float* __restrict__ colCar, int n) {
    const int c = blockIdx.x, b = blockIdx.y;
    const int t = threadIdx.x;
    __shared__ float TTl[NT];
    if (t >= 64) {
        const int j = t - 64;
        if (j < NT) {
            float s = 0.f;
            for (int v = j; v < c; ++v) s += TS[((size_t)b * NT + j) * NT + v];
            TTl[j] = s;  // tos[j][c]
        }
    }
    __syncthreads();
    if (t < 64) {
        const int p = c * 64 + t;
        float sv[NT];
#pragma unroll
        for (int v = 0; v < NT; ++v)
            sv[v] = (v >= c) ? rowW[((size_t)b * NT + v) * n + p] : 0.f;
        float acc = 0.f;
#pragma unroll
        for (int bq = 0; bq < NT; ++bq) {
            rowOff[((size_t)b * NT + bq) * n + p] = acc;
            acc += sv[bq];
        }
    } else {
        const int j = t - 64;
        const int q0 = c * 64;
        colCar[((size_t)b * NT + c) * n + q0 + j] = 0.f;
        if (c > 0) {
            float rv[NT];
#pragma unroll
            for (int bi = 1; bi < NT; ++bi)
                rv[bi] = (bi <= c) ? colW[((size_t)b * NT + bi) * n + q0 + j] : 0.f;
            float carry = 0.f;
#pragma unroll
            for (int bi = NT - 1; bi >= 1; --bi) {
                if (bi <= c) {
                    float cw = rv[bi];
#pragma unroll
                    for (int d = 1; d < 64; d <<= 1) {
                        float o2 = __shfl_up(cw, d, 64);
                        if (j >= d) cw += o2;
                    }
                    carry += cw + TTl[bi];
                    colCar[((size_t)b * NT + (bi - 1)) * n + q0 + j] = carry;
                }
            }
        }
    }
}

__global__ __launch_bounds__(256) void k4_tile(const float* __restrict__ D,
                                               float* __restrict__ out,
                                               const float* __restrict__ rowOff,
                                               const float* __restrict__ colCar, int n) {
    int bi, bq;
    tri_decode(blockIdx.x, bi, bq);
    const int b = blockIdx.y;
    const int i0 = bi * 64, q0 = bq * 64;
    const bool dg = (bi == bq);
    const size_t nn = (size_t)n * n;
    const float* Db = D + (size_t)b * nn;
    float* Ob = out + (size_t)b * nn;
    __shared__ float Al[64 * PD];
    __shared__ float st1[4 * 64], st2[4 * 64];
    __shared__ float rOl[64], cCl[64];
    const int t = threadIdx.x;
    const int c4 = (t & 15) * 4, r0 = t >> 4;
    float4 va[4];
#pragma unroll
    for (int m = 0; m < 4; ++m)
        va[m] = *(const float4*)&Ob[(size_t)(i0 + r0 + 16 * m) * n + q0 + c4];
    if (t < 64) rOl[t] = rowOff[((size_t)b * NT + bq) * n + i0 + t];
    else if (t < 128) cCl[t - 64] = colCar[((size_t)b * NT + bi) * n + q0 + (t - 64)];
#pragma unroll
    for (int m = 0; m < 4; ++m) {
        const int r = r0 + 16 * m;
        Al[r * PD + c4 + 0] = va[m].x;
        Al[r * PD + c4 + 1] = va[m].y;
        Al[r * PD + c4 + 2] = va[m].z;
        Al[r * PD + c4 + 3] = va[m].w;
    }
    __syncthreads();
    const int lp = t & 63, s = t >> 6;
    // row prefix: row lp, col segment [16s, 16s+16)
    float v[16];
    {
        float run = 0.f;
#pragma unroll
        for (int k = 0; k < 16; ++k) {
            run += Al[lp * PD + 16 * s + k];
            v[k] = run;
        }
        st1[s * 64 + lp] = run;
    }
    __syncthreads();
    {
        float off = rOl[lp];
        if (s > 0) off += st1[0 * 64 + lp];
        if (s > 1) off += st1[1 * 64 + lp];
        if (s > 2) off += st1[2 * 64 + lp];
#pragma unroll
        for (int k = 0; k < 16; ++k) Al[lp * PD + 16 * s + k] = v[k] + off;
    }
    __syncthreads();
    // col suffix: column lp, row segment [16s, 16s+16)
    float g[16];
#pragma unroll
    for (int k = 0; k < 16; ++k) g[k] = Al[(16 * s + k) * PD + lp];
#pragma unroll
    for (int k = 14; k >= 0; --k) g[k] += g[k + 1];
    st2[s * 64 + lp] = g[0];
    __syncthreads();
    {
        float off = cCl[lp];
        if (s < 1) off += st2[1 * 64 + lp];
        if (s < 2) off += st2[2 * 64 + lp];
        if (s < 3) off += st2[3 * 64 + lp];
#pragma unroll
        for (int k = 0; k < 16; ++k) Al[lp * PD + 16 * s + k] = g[k] + off;  // Al[c][r]=G[r][c]
    }
    __syncthreads();
    if (!dg) {
#pragma unroll
        for (int m = 0; m < 4; ++m) {
            const int r = r0 + 16 * m;
            float4 uu;
            uu.x = Al[(c4 + 0) * PD + r];
            uu.y = Al[(c4 + 1) * PD + r];
            uu.z = Al[(c4 + 2) * PD + r];
            uu.w = Al[(c4 + 3) * PD + r];
            *(float4*)&Ob[(size_t)(i0 + r) * n + q0 + c4] = uu;
            float4 l4;
            l4.x = Al[r * PD + c4 + 0];
            l4.y = Al[r * PD + c4 + 1];
            l4.z = Al[r * PD + c4 + 2];
            l4.w = Al[r * PD + c4 + 3];
            // boundary subdiagonal element out[q0][q0-1] lives in tile (bi, bi+1)
            if (bq == bi + 1 && r == 0 && c4 == 60) l4.w = Db[(size_t)q0 * n + (q0 - 1)];
            *(float4*)&Ob[(size_t)(q0 + r) * n + i0 + c4] = l4;
        }
    } else {
#pragma unroll
        for (int m = 0; m < 16; ++m) {
            const int idx = 256 * m + t;
            const int rr = idx >> 6, cc = idx & 63;
            float val = (cc >= rr) ? Al[cc * PD + rr] : Al[rr * PD + cc];
            if (cc == rr - 1) val = Db[(size_t)(i0 + rr) * n + (i0 + cc)];
            Ob[(size_t)(i0 + rr) * n + q0 + cc] = val;
        }
    }
}

extern "C" void kernel_launch(void* const* d_in, const int* in_sizes, int n_in,
                              void* d_out, int out_size, void* d_ws, size_t ws_size,
                              hipStream_t stream) {
    const float* D = (const float*)d_in[0];
    float* out = (float*)d_out;
    const int n = 2048;
    const int B = in_sizes[0] / (n * n);
    const int NTRI = NT * (NT + 1) / 2;  // 528

    float* ws = (float*)d_ws;
    const size_t szC = (size_t)B * NT * n;
    float* rowW   = ws;
    float* colW   = rowW + szC;
    float* TS     = colW + szC;
    float* rowOff = TS + (size_t)B * NT * NT;
    float* colCar = rowOff + szC;

    k1_w<<<dim3(NTRI, B), dim3(256), 0, stream>>>(D, out, rowW, colW, TS, n);
    k23<<<dim3(NT, B), dim3(128), 0, stream>>>(rowW, colW, TS, rowOff, colCar, n);
    k4_tile<<<dim3(NTRI, B), dim3(256), 0, stream>>>(D, out, rowOff, colCar, n);
}

// Round 6
// 76.847 us; speedup vs baseline: 2.4377x; 1.1456x over previous
//
#include <hip/hip_runtime.h>

// out[b][i][j] = G[min(i,j)][max(i,j)], G[i][j] = sum_{i<=p<=q<=j} W[p][q],
// W[p][p]=D[p][p], W[p][q]=D[p][q]+D[q][p] (q>p), W=0 below diag;
// out[b][i][i-1]=D[b][i][i-1].
//
// k1 (528 upper tiles/batch): forms masked W tile, row-PREFIXES it in registers
//     (64-wide, via 16-lane shfl scan), stores W~ into d_out upper positions;
//     emits rowW[v][p] (= prefix tail), colW[u][j] (raw col sums), TS[u][v].
// k4 (528 tiles): wave-specialized preamble computes rowOff (waves 0,2) and
//     colCar (waves 1,3, incl. per-bi' colW prefix scans + TS tos) while W~ is
//     staged to LDS; then col-suffix scan, dual-triangle write, inline patches.

#define NT 32
#define PD 65

__device__ __forceinline__ void tri_decode(int m, int& u, int& v) {
    int u_ = 0, rem = m;
    while (rem >= NT - u_) { rem -= NT - u_; ++u_; }
    u = u_;
    v = u_ + rem;
}

__global__ __launch_bounds__(256) void k1_w(const float* __restrict__ D,
                                            float* __restrict__ Mout,
                                            float* __restrict__ rowW,
                                            float* __restrict__ colW,
                                            float* __restrict__ TS, int n) {
    int u, v;
    tri_decode(blockIdx.x, u, v);
    const int b = blockIdx.y;
    const size_t nn = (size_t)n * n;
    const float* Db = D + (size_t)b * nn;
    float* Mb = Mout + (size_t)b * nn;
    __shared__ float Tl[64 * PD];
    __shared__ float s1[64];
    __shared__ float s2[4 * 64];
    const int t = threadIdx.x;
    const int c4 = (t & 15) * 4, r0 = t >> 4;
    const int i0 = u * 64, q0 = v * 64;
    const bool dg = (u == v);
    float4 va[4], vb[4];
#pragma unroll
    for (int m = 0; m < 4; ++m)
        va[m] = *(const float4*)&Db[(size_t)(i0 + r0 + 16 * m) * n + q0 + c4];
    if (!dg) {
#pragma unroll
        for (int m = 0; m < 4; ++m)
            vb[m] = *(const float4*)&Db[(size_t)(q0 + r0 + 16 * m) * n + i0 + c4];
    } else {
#pragma unroll
        for (int m = 0; m < 4; ++m) vb[m] = va[m];
    }
#pragma unroll
    for (int m = 0; m < 4; ++m) {
        const int rr = r0 + 16 * m;
        Tl[rr * PD + c4 + 0] = vb[m].x;
        Tl[rr * PD + c4 + 1] = vb[m].y;
        Tl[rr * PD + c4 + 2] = vb[m].z;
        Tl[rr * PD + c4 + 3] = vb[m].w;
    }
    __syncthreads();
    const int lg = t & 15;
    float cs0 = 0.f, cs1 = 0.f, cs2 = 0.f, cs3 = 0.f;
#pragma unroll
    for (int m = 0; m < 4; ++m) {
        const int r = r0 + 16 * m;
        float w0 = va[m].x + Tl[(c4 + 0) * PD + r];
        float w1 = va[m].y + Tl[(c4 + 1) * PD + r];
        float w2 = va[m].z + Tl[(c4 + 2) * PD + r];
        float w3 = va[m].w + Tl[(c4 + 3) * PD + r];
        if (dg) {
            w0 = (c4 + 0 > r) ? w0 : ((c4 + 0 == r) ? va[m].x : 0.f);
            w1 = (c4 + 1 > r) ? w1 : ((c4 + 1 == r) ? va[m].y : 0.f);
            w2 = (c4 + 2 > r) ? w2 : ((c4 + 2 == r) ? va[m].z : 0.f);
            w3 = (c4 + 3 > r) ? w3 : ((c4 + 3 == r) ? va[m].w : 0.f);
        }
        cs0 += w0; cs1 += w1; cs2 += w2; cs3 += w3;
        // in-register row prefix (4 elems) + 16-lane segment scan => full 64 prefix
        const float p0 = w0, p1 = p0 + w1, p2 = p1 + w2, p3 = p2 + w3;
        const float totseg = p3;
        float incl = totseg;
#pragma unroll
        for (int d = 1; d < 16; d <<= 1) {
            const float sh = __shfl_up(incl, d, 16);
            if (lg >= d) incl += sh;
        }
        const float base = incl - totseg;
        float4 wv = {p0 + base, p1 + base, p2 + base, p3 + base};
        *(float4*)&Mb[(size_t)(i0 + r) * n + q0 + c4] = wv;
        if (lg == 15) s1[r] = incl;  // full (masked) row sum
    }
    cs0 += __shfl_xor(cs0, 16, 64); cs0 += __shfl_xor(cs0, 32, 64);
    cs1 += __shfl_xor(cs1, 16, 64); cs1 += __shfl_xor(cs1, 32, 64);
    cs2 += __shfl_xor(cs2, 16, 64); cs2 += __shfl_xor(cs2, 32, 64);
    cs3 += __shfl_xor(cs3, 16, 64); cs3 += __shfl_xor(cs3, 32, 64);
    const int wv_ = t >> 6, l = t & 63;
    if (l < 16) {
        s2[wv_ * 64 + 4 * l + 0] = cs0;
        s2[wv_ * 64 + 4 * l + 1] = cs1;
        s2[wv_ * 64 + 4 * l + 2] = cs2;
        s2[wv_ * 64 + 4 * l + 3] = cs3;
    }
    __syncthreads();
    if (t < 64) {
        rowW[((size_t)b * NT + v) * n + i0 + t] = s1[t];
        float cw = s2[t] + s2[64 + t] + s2[128 + t] + s2[192 + t];
        colW[((size_t)b * NT + u) * n + q0 + t] = cw;
        float ts = cw;
        ts += __shfl_xor(ts, 1, 64);
        ts += __shfl_xor(ts, 2, 64);
        ts += __shfl_xor(ts, 4, 64);
        ts += __shfl_xor(ts, 8, 64);
        ts += __shfl_xor(ts, 16, 64);
        ts += __shfl_xor(ts, 32, 64);
        if (t == 0) TS[((size_t)b * NT + u) * NT + v] = ts;
    }
}

__global__ __launch_bounds__(256) void k4_tile(const float* __restrict__ D,
                                               float* __restrict__ out,
                                               const float* __restrict__ rowW,
                                               const float* __restrict__ colW,
                                               const float* __restrict__ TS, int n) {
    int bi, bq;
    tri_decode(blockIdx.x, bi, bq);
    const int b = blockIdx.y;
    const int i0 = bi * 64, q0 = bq * 64;
    const bool dg = (bi == bq);
    const size_t nn = (size_t)n * n;
    const float* Db = D + (size_t)b * nn;
    float* Ob = out + (size_t)b * nn;
    __shared__ float Al[64 * PD];
    __shared__ float st2[4 * 64];
    __shared__ float rOlA[64], rOlB[64], cClA[64], cClB[64];
    const int t = threadIdx.x;
    const int c4 = (t & 15) * 4, r0 = t >> 4;
    float4 va[4];
#pragma unroll
    for (int m = 0; m < 4; ++m)
        va[m] = *(const float4*)&Ob[(size_t)(i0 + r0 + 16 * m) * n + q0 + c4];
    const int w = t >> 6, l = t & 63;
    // wave-specialized preamble (concurrent with staging loads)
    if ((w & 1) == 0) {
        // waves 0,2: rowOff halves: sum rowW[v][i0+l] over v in [bi, bq), parity split
        float acc = 0.f;
        for (int v2 = bi + (w >> 1); v2 < bq; v2 += 2)
            acc += rowW[((size_t)b * NT + v2) * n + i0 + l];
        (w == 0 ? rOlA : rOlB)[l] = acc;
    } else {
        // waves 1,3: colCar halves over bi' in (bi, bq], parity split
        const int base = bi + 1 + ((w - 1) >> 1);  // w1: bi+1, w3: bi+2
        float tosv = 0.f;
        {
            const int bip = base + 2 * l;
            if (bip <= bq)
                for (int v2 = bip; v2 < bq; ++v2)
                    tosv += TS[((size_t)b * NT + bip) * NT + v2];
        }
        float carry = 0.f;
        for (int k = 0; base + 2 * k <= bq; ++k) {
            const int bip = base + 2 * k;
            float cw = colW[((size_t)b * NT + bip) * n + q0 + l];
#pragma unroll
            for (int d2 = 1; d2 < 64; d2 <<= 1) {
                const float sh = __shfl_up(cw, d2, 64);
                if (l >= d2) cw += sh;
            }
            carry += cw + __shfl(tosv, k, 64);
        }
        (w == 1 ? cClA : cClB)[l] = carry;
    }
#pragma unroll
    for (int m = 0; m < 4; ++m) {
        const int r = r0 + 16 * m;
        Al[r * PD + c4 + 0] = va[m].x;
        Al[r * PD + c4 + 1] = va[m].y;
        Al[r * PD + c4 + 2] = va[m].z;
        Al[r * PD + c4 + 3] = va[m].w;
    }
    __syncthreads();
    const int lp = t & 63, s = t >> 6;
    // col suffix: column lp, row segment [16s,16s+16); W~ already row-prefixed
    float g[16];
#pragma unroll
    for (int k = 0; k < 16; ++k) {
        const int r = 16 * s + k;
        g[k] = Al[r * PD + lp] + rOlA[r] + rOlB[r];
    }
#pragma unroll
    for (int k = 14; k >= 0; --k) g[k] += g[k + 1];
    st2[s * 64 + lp] = g[0];
    __syncthreads();
    {
        float off = cClA[lp] + cClB[lp];
        if (s < 1) off += st2[64 + lp];
        if (s < 2) off += st2[128 + lp];
        if (s < 3) off += st2[192 + lp];
#pragma unroll
        for (int k = 0; k < 16; ++k) Al[lp * PD + 16 * s + k] = g[k] + off;  // Al[c][r]=G[r][c]
    }
    __syncthreads();
    if (!dg) {
#pragma unroll
        for (int m = 0; m < 4; ++m) {
            const int r = r0 + 16 * m;
            float4 uu;
            uu.x = Al[(c4 + 0) * PD + r];
            uu.y = Al[(c4 + 1) * PD + r];
            uu.z = Al[(c4 + 2) * PD + r];
            uu.w = Al[(c4 + 3) * PD + r];
            *(float4*)&Ob[(size_t)(i0 + r) * n + q0 + c4] = uu;
            float4 l4;
            l4.x = Al[r * PD + c4 + 0];
            l4.y = Al[r * PD + c4 + 1];
            l4.z = Al[r * PD + c4 + 2];
            l4.w = Al[r * PD + c4 + 3];
            // boundary subdiagonal element out[q0][q0-1] lives in tile (bi, bi+1)
            if (bq == bi + 1 && r == 0 && c4 == 60) l4.w = Db[(size_t)q0 * n + (q0 - 1)];
            *(float4*)&Ob[(size_t)(q0 + r) * n + i0 + c4] = l4;
        }
    } else {
#pragma unroll
        for (int m = 0; m < 16; ++m) {
            const int idx = 256 * m + t;
            const int rr = idx >> 6, cc = idx & 63;
            float val = (cc >= rr) ? Al[cc * PD + rr] : Al[rr * PD + cc];
            if (cc == rr - 1) val = Db[(size_t)(i0 + rr) * n + (i0 + cc)];
            Ob[(size_t)(i0 + rr) * n + q0 + cc] = val;
        }
    }
}

extern "C" void kernel_launch(void* const* d_in, const int* in_sizes, int n_in,
                              void* d_out, int out_size, void* d_ws, size_t ws_size,
                              hipStream_t stream) {
    const float* D = (const float*)d_in[0];
    float* out = (float*)d_out;
    const int n = 2048;
    const int B = in_sizes[0] / (n * n);
    const int NTRI = NT * (NT + 1) / 2;  // 528

    float* ws = (float*)d_ws;
    const size_t szC = (size_t)B * NT * n;
    float* rowW = ws;
    float* colW = rowW + szC;
    float* TS   = colW + szC;

    k1_w<<<dim3(NTRI, B), dim3(256), 0, stream>>>(D, out, rowW, colW, TS, n);
    k4_tile<<<dim3(NTRI, B), dim3(256), 0, stream>>>(D, out, rowW, colW, TS, n);
}

// Round 7
// 72.981 us; speedup vs baseline: 2.5668x; 1.0530x over previous
//
#include <hip/hip_runtime.h>

// out[b][i][j] = G[min(i,j)][max(i,j)], G[i][j] = sum_{i<=p<=q<=j} W[p][q],
// W[p][p]=D[p][p], W[p][q]=D[p][q]+D[q][p] (q>p), W=0 below diag;
// out[b][i][i-1]=D[b][i][i-1].
//
// k1 (528 upper tiles/batch): forms masked W tile, row-prefixes it in registers
//     (16-lane shfl segment scan), stores W~ into d_out upper positions; emits
//     rowW[v][p] (masked row sums), colWP[u][j] (PREFIX-scanned col sums), TS[u][v].
// k4 (528 tiles): W~ read directly to registers (coalesced, issued early);
//     wave-specialized preamble: waves 0,2 sum rowW -> rowOff; waves 1,3 sum
//     colWP + TS-triangle (all independent loads, no scan chains) -> colCar;
//     col-suffix in registers, direct upper stores, LDS transpose for lower.

#define NT 32
#define PD 65

__device__ __forceinline__ void tri_decode(int m, int& u, int& v) {
    int u_ = 0, rem = m;
    while (rem >= NT - u_) { rem -= NT - u_; ++u_; }
    u = u_;
    v = u_ + rem;
}

__global__ __launch_bounds__(256) void k1_w(const float* __restrict__ D,
                                            float* __restrict__ Mout,
                                            float* __restrict__ rowW,
                                            float* __restrict__ colWP,
                                            float* __restrict__ TS, int n) {
    int u, v;
    tri_decode(blockIdx.x, u, v);
    const int b = blockIdx.y;
    const size_t nn = (size_t)n * n;
    const float* Db = D + (size_t)b * nn;
    float* Mb = Mout + (size_t)b * nn;
    __shared__ float Tl[64 * PD];
    __shared__ float s1[64];
    __shared__ float s2[4 * 64];
    const int t = threadIdx.x;
    const int c4 = (t & 15) * 4, r0 = t >> 4;
    const int i0 = u * 64, q0 = v * 64;
    const bool dg = (u == v);
    float4 va[4], vb[4];
#pragma unroll
    for (int m = 0; m < 4; ++m)
        va[m] = *(const float4*)&Db[(size_t)(i0 + r0 + 16 * m) * n + q0 + c4];
    if (!dg) {
#pragma unroll
        for (int m = 0; m < 4; ++m)
            vb[m] = *(const float4*)&Db[(size_t)(q0 + r0 + 16 * m) * n + i0 + c4];
    } else {
#pragma unroll
        for (int m = 0; m < 4; ++m) vb[m] = va[m];
    }
#pragma unroll
    for (int m = 0; m < 4; ++m) {
        const int rr = r0 + 16 * m;
        Tl[rr * PD + c4 + 0] = vb[m].x;
        Tl[rr * PD + c4 + 1] = vb[m].y;
        Tl[rr * PD + c4 + 2] = vb[m].z;
        Tl[rr * PD + c4 + 3] = vb[m].w;
    }
    __syncthreads();
    const int lg = t & 15;
    float cs0 = 0.f, cs1 = 0.f, cs2 = 0.f, cs3 = 0.f;
#pragma unroll
    for (int m = 0; m < 4; ++m) {
        const int r = r0 + 16 * m;
        float w0 = va[m].x + Tl[(c4 + 0) * PD + r];
        float w1 = va[m].y + Tl[(c4 + 1) * PD + r];
        float w2 = va[m].z + Tl[(c4 + 2) * PD + r];
        float w3 = va[m].w + Tl[(c4 + 3) * PD + r];
        if (dg) {
            w0 = (c4 + 0 > r) ? w0 : ((c4 + 0 == r) ? va[m].x : 0.f);
            w1 = (c4 + 1 > r) ? w1 : ((c4 + 1 == r) ? va[m].y : 0.f);
            w2 = (c4 + 2 > r) ? w2 : ((c4 + 2 == r) ? va[m].z : 0.f);
            w3 = (c4 + 3 > r) ? w3 : ((c4 + 3 == r) ? va[m].w : 0.f);
        }
        cs0 += w0; cs1 += w1; cs2 += w2; cs3 += w3;
        // in-register row prefix (4 elems) + 16-lane segment scan => full 64 prefix
        const float p0 = w0, p1 = p0 + w1, p2 = p1 + w2, p3 = p2 + w3;
        const float totseg = p3;
        float incl = totseg;
#pragma unroll
        for (int d = 1; d < 16; d <<= 1) {
            const float sh = __shfl_up(incl, d, 16);
            if (lg >= d) incl += sh;
        }
        const float base = incl - totseg;
        float4 wv = {p0 + base, p1 + base, p2 + base, p3 + base};
        *(float4*)&Mb[(size_t)(i0 + r) * n + q0 + c4] = wv;
        if (lg == 15) s1[r] = incl;  // full (masked) row sum
    }
    cs0 += __shfl_xor(cs0, 16, 64); cs0 += __shfl_xor(cs0, 32, 64);
    cs1 += __shfl_xor(cs1, 16, 64); cs1 += __shfl_xor(cs1, 32, 64);
    cs2 += __shfl_xor(cs2, 16, 64); cs2 += __shfl_xor(cs2, 32, 64);
    cs3 += __shfl_xor(cs3, 16, 64); cs3 += __shfl_xor(cs3, 32, 64);
    const int wv_ = t >> 6, l = t & 63;
    if (l < 16) {
        s2[wv_ * 64 + 4 * l + 0] = cs0;
        s2[wv_ * 64 + 4 * l + 1] = cs1;
        s2[wv_ * 64 + 4 * l + 2] = cs2;
        s2[wv_ * 64 + 4 * l + 3] = cs3;
    }
    __syncthreads();
    if (t < 64) {
        rowW[((size_t)b * NT + v) * n + i0 + t] = s1[t];
        float cw = s2[t] + s2[64 + t] + s2[128 + t] + s2[192 + t];
        // inclusive prefix scan over the 64 columns
#pragma unroll
        for (int d = 1; d < 64; d <<= 1) {
            const float sh = __shfl_up(cw, d, 64);
            if (t >= d) cw += sh;
        }
        colWP[((size_t)b * NT + u) * n + q0 + t] = cw;
        if (t == 63) TS[((size_t)b * NT + u) * NT + v] = cw;  // tile total
    }
}

__global__ __launch_bounds__(256) void k4_tile(const float* __restrict__ D,
                                               float* __restrict__ out,
                                               const float* __restrict__ rowW,
                                               const float* __restrict__ colWP,
                                               const float* __restrict__ TS, int n) {
    int bi, bq;
    tri_decode(blockIdx.x, bi, bq);
    const int b = blockIdx.y;
    const int i0 = bi * 64, q0 = bq * 64;
    const bool dg = (bi == bq);
    const size_t nn = (size_t)n * n;
    const float* Db = D + (size_t)b * nn;
    float* Ob = out + (size_t)b * nn;
    __shared__ float Al[64 * PD];   // G^T: Al[c*PD+r] = G[r][c]
    __shared__ float st2[4 * 64];
    __shared__ float rOlA[64], rOlB[64], cClA[64], cClB[64];
    const int t = threadIdx.x;
    const int w = t >> 6, l = t & 63;
    const int s = w, lp = l;
    // W~ tile reads: coalesced (fixed row, lanes across cols), issued before preamble
    float wt[16];
#pragma unroll
    for (int k = 0; k < 16; ++k)
        wt[k] = Ob[(size_t)(i0 + 16 * s + k) * n + q0 + lp];
    // wave-specialized preamble: pure sums, no dependent scan chains
    if ((w & 1) == 0) {
        float acc = 0.f;
        for (int v2 = bi + (w >> 1); v2 < bq; v2 += 2)
            acc += rowW[((size_t)b * NT + v2) * n + i0 + l];
        (w == 0 ? rOlA : rOlB)[l] = acc;
    } else {
        const int base = bi + 1 + ((w - 1) >> 1);  // w1: bi+1, w3: bi+2
        float acc = 0.f, tacc = 0.f;
        for (int bip = base; bip <= bq; bip += 2) {
            acc += colWP[((size_t)b * NT + bip) * n + q0 + l];
            const int v2 = bip + l;              // tos[bip][bq] spread over lanes
            if (v2 < bq) tacc += TS[((size_t)b * NT + bip) * NT + v2];
        }
        tacc += __shfl_xor(tacc, 1, 64);
        tacc += __shfl_xor(tacc, 2, 64);
        tacc += __shfl_xor(tacc, 4, 64);
        tacc += __shfl_xor(tacc, 8, 64);
        tacc += __shfl_xor(tacc, 16, 64);
        tacc += __shfl_xor(tacc, 32, 64);
        (w == 1 ? cClA : cClB)[l] = acc + tacc;
    }
    __syncthreads();
    // col suffix over register column fragment (rows 16s..16s+15 of col lp)
    float g[16];
#pragma unroll
    for (int k = 0; k < 16; ++k) {
        const int r = 16 * s + k;
        g[k] = wt[k] + rOlA[r] + rOlB[r];
    }
#pragma unroll
    for (int k = 14; k >= 0; --k) g[k] += g[k + 1];
    st2[s * 64 + lp] = g[0];
    __syncthreads();
    float off = cClA[lp] + cClB[lp];
    if (s < 1) off += st2[64 + lp];
    if (s < 2) off += st2[128 + lp];
    if (s < 3) off += st2[192 + lp];
    if (!dg) {
        // direct upper stores (coalesced per row) + G^T to LDS for lower mirror
#pragma unroll
        for (int k = 0; k < 16; ++k) {
            const float gv = g[k] + off;
            Ob[(size_t)(i0 + 16 * s + k) * n + q0 + lp] = gv;
            Al[lp * PD + 16 * s + k] = gv;
        }
        __syncthreads();
        const int c4 = (t & 15) * 4, r0 = t >> 4;
#pragma unroll
        for (int m = 0; m < 4; ++m) {
            const int r = r0 + 16 * m;
            float4 l4;
            l4.x = Al[r * PD + c4 + 0];
            l4.y = Al[r * PD + c4 + 1];
            l4.z = Al[r * PD + c4 + 2];
            l4.w = Al[r * PD + c4 + 3];
            // boundary subdiagonal element out[q0][q0-1] lives in tile (bi, bi+1)
            if (bq == bi + 1 && r == 0 && c4 == 60) l4.w = Db[(size_t)q0 * n + (q0 - 1)];
            *(float4*)&Ob[(size_t)(q0 + r) * n + i0 + c4] = l4;
        }
    } else {
#pragma unroll
        for (int k = 0; k < 16; ++k) Al[lp * PD + 16 * s + k] = g[k] + off;
        __syncthreads();
#pragma unroll
        for (int m = 0; m < 16; ++m) {
            const int idx = 256 * m + t;
            const int rr = idx >> 6, cc = idx & 63;
            float val = (cc >= rr) ? Al[cc * PD + rr] : Al[rr * PD + cc];
            if (cc == rr - 1) val = Db[(size_t)(i0 + rr) * n + (i0 + cc)];
            Ob[(size_t)(i0 + rr) * n + q0 + cc] = val;
        }
    }
}

extern "C" void kernel_launch(void* const* d_in, const int* in_sizes, int n_in,
                              void* d_out, int out_size, void* d_ws, size_t ws_size,
                              hipStream_t stream) {
    const float* D = (const float*)d_in[0];
    float* out = (float*)d_out;
    const int n = 2048;
    const int B = in_sizes[0] / (n * n);
    const int NTRI = NT * (NT + 1) / 2;  // 528

    float* ws = (float*)d_ws;
    const size_t szC = (size_t)B * NT * n;
    float* rowW  = ws;
    float* colWP = rowW + szC;
    float* TS    = colWP + szC;

    k1_w<<<dim3(NTRI, B), dim3(256), 0, stream>>>(D, out, rowW, colWP, TS, n);
    k4_tile<<<dim3(NTRI, B), dim3(256), 0, stream>>>(D, out, rowW, colWP, TS, n);
}